// Round 3
// baseline (93.145 us; speedup 1.0000x reference)
//
#include <hip/hip_runtime.h>

// PairwiseRankingLoss: B=128 rows, L=1024.
// loss = sum_{b, pos i, neg j} relu(1 - s[b,i] + s[b,j]) / max(num_pairs, 1)
//
// Single fused kernel: grid = B*SPLIT blocks. Block (b, s) computes the hinge
// sum over (all i in row b) x (j in slice s), branchless via sentinels, then
// atomically accumulates {sum, cpos*cneg_slice} into d_ws. The last block to
// finish (atomic counter) writes the final normalized loss.

#define PRL_B 128
#define PRL_L 1024
#define SPLIT 16
#define JS (PRL_L / SPLIT)      // 64 j's per block
#define NBLK (PRL_B * SPLIT)    // 2048 blocks

__global__ __launch_bounds__(256) void prl_fused(
    const float* __restrict__ y_pred,
    const int*   __restrict__ y_true,
    float*              gsum,      // ws: device-scope accumulators (pre-zeroed)
    unsigned long long* gpairs,
    unsigned int*       gcount,
    float* __restrict__ out)
{
    __shared__ float s_d[JS];      // 1 + score for negatives, -3e38 otherwise
    __shared__ float s_wsum[4];
    __shared__ int   s_wpos[4];
    __shared__ int   s_wneg[4];

    const int blk = blockIdx.x;
    const int b   = blk >> 4;             // / SPLIT
    const int s   = blk & (SPLIT - 1);
    const int t   = threadIdx.x;
    const int js  = s * JS;

    // Vectorized staging: one float4 + one int4 per thread covers the row.
    const float4 sc = ((const float4*)(y_pred + (size_t)b * PRL_L))[t];
    const int4   lv = ((const int4*)  (y_true + (size_t)b * PRL_L))[t];

    // Candidate-positive values (sentinel +3e38 -> pair contributes 0).
    float p[4];
    p[0] = (lv.x == 1) ? sc.x : 3.0e38f;
    p[1] = (lv.y == 1) ? sc.y : 3.0e38f;
    p[2] = (lv.z == 1) ? sc.z : 3.0e38f;
    p[3] = (lv.w == 1) ? sc.w : 3.0e38f;
    int cpos = (lv.x == 1) + (lv.y == 1) + (lv.z == 1) + (lv.w == 1);
    int cneg = 0;

    // Slice staging from registers: threads [js/4, js/4+16) own the slice.
    const int base = js >> 2;
    if ((unsigned)(t - base) < (unsigned)(JS / 4)) {
        float4 d;
        d.x = (lv.x == 0) ? (1.0f + sc.x) : -3.0e38f;
        d.y = (lv.y == 0) ? (1.0f + sc.y) : -3.0e38f;
        d.z = (lv.z == 0) ? (1.0f + sc.z) : -3.0e38f;
        d.w = (lv.w == 0) ? (1.0f + sc.w) : -3.0e38f;
        ((float4*)s_d)[t - base] = d;
        cneg = (lv.x == 0) + (lv.y == 0) + (lv.z == 0) + (lv.w == 0);
    }
    __syncthreads();

    // Hot loop: 16 wave-uniform float4 LDS broadcasts, 48 VALU ops each.
    float acc[4] = {0.f, 0.f, 0.f, 0.f};
    const float4* d4 = (const float4*)s_d;
#pragma unroll
    for (int c = 0; c < JS / 4; ++c) {
        const float4 d = d4[c];
#pragma unroll
        for (int k = 0; k < 4; ++k) {
            const float m0 = fmaxf(d.x - p[k], 0.0f) + fmaxf(d.y - p[k], 0.0f);
            const float m1 = fmaxf(d.z - p[k], 0.0f) + fmaxf(d.w - p[k], 0.0f);
            acc[k] += m0 + m1;
        }
    }
    float local = (acc[0] + acc[1]) + (acc[2] + acc[3]);

    // Block reduction: wave shuffle then LDS combine.
#pragma unroll
    for (int off = 32; off >= 1; off >>= 1) {
        local += __shfl_down(local, off, 64);
        cpos  += __shfl_down(cpos,  off, 64);
        cneg  += __shfl_down(cneg,  off, 64);
    }
    const int wave = t >> 6;
    if ((t & 63) == 0) { s_wsum[wave] = local; s_wpos[wave] = cpos; s_wneg[wave] = cneg; }
    __syncthreads();

    if (t == 0) {
        float rs = 0.f; int rp = 0, rn = 0;
#pragma unroll
        for (int w = 0; w < 4; ++w) { rs += s_wsum[w]; rp += s_wpos[w]; rn += s_wneg[w]; }
        // rp = full-row pos count (block covers all i); rn = this slice's negs.
        // sum over slices of rp*rn_s == rp * nneg_row, so per-block add is exact.
        atomicAdd(gsum, rs);
        atomicAdd(gpairs, (unsigned long long)(rp * rn));
        __threadfence();
        const unsigned old = atomicAdd(gcount, 1u);
        if (old == NBLK - 1) {
            // All blocks' accumulations are complete and visible (atomics at
            // device coherence point; read back through atomics).
            const float              total = atomicAdd(gsum, 0.0f);
            const unsigned long long pairs = atomicAdd(gpairs, 0ULL);
            out[0] = (pairs > 0) ? (total / fmaxf((float)pairs, 1.0f)) : total;
        }
    }
}

extern "C" void kernel_launch(void* const* d_in, const int* in_sizes, int n_in,
                              void* d_out, int out_size, void* d_ws, size_t ws_size,
                              hipStream_t stream) {
    const float* y_pred = (const float*)d_in[0];
    const int*   y_true = (const int*)d_in[1];
    float* out = (float*)d_out;

    // ws layout (16B-aligned): [0] float gsum; [8] u64 gpairs; [16] u32 gcount
    float*              gsum   = (float*)d_ws;
    unsigned long long* gpairs = (unsigned long long*)((char*)d_ws + 8);
    unsigned int*       gcount = (unsigned int*)((char*)d_ws + 16);

    hipMemsetAsync(d_ws, 0, 24, stream);  // memset node: zero accumulators per call
    prl_fused<<<NBLK, 256, 0, stream>>>(y_pred, y_true, gsum, gpairs, gcount, out);
}

// Round 4
// 48.174 us; speedup vs baseline: 1.9335x; 1.9335x over previous
//
#include <hip/hip_runtime.h>

// PairwiseRankingLoss: B=128 rows, L=1024.
// loss = sum_{b, pos i, neg j} relu(1 - s[b,i] + s[b,j]) / max(num_pairs, 1)
//
// Single fused kernel, contention-free finish:
//  - grid = B*SPLIT = 2048 blocks; block (b,s) computes hinge over
//    (all i in row b) x (j in slice s), branchless via sentinels.
//  - per-block partials -> DISTINCT ws slots (plain stores, no atomics).
//  - completion: 32 group counters (one 128-B line each, 64 incs apiece,
//    parallel across L2 banks) -> 1 top counter (32 incs). Last block
//    reduces all 2048 partials (16 KB L2) and writes the loss.

#define PRL_B 128
#define PRL_L 1024
#define SPLIT 16
#define JS    (PRL_L / SPLIT)   // 64 j's per block
#define NBLK  (PRL_B * SPLIT)   // 2048 blocks
#define GRP   64                // blocks per level-1 group
#define NGRP  (NBLK / GRP)      // 32 groups
#define C1_STRIDE 32            // u32 stride between group counters (128 B)

__global__ __launch_bounds__(256) void prl_fused(
    const float* __restrict__ y_pred,
    const int*   __restrict__ y_true,
    unsigned int* gc1,          // [NGRP * C1_STRIDE], pre-zeroed
    unsigned int* gc2,          // [1], pre-zeroed
    float*        bsum,         // [NBLK]
    int*          bpairs,       // [NBLK]
    float* __restrict__ out)
{
    __shared__ float s_d[JS];
    __shared__ float s_wsum[4];
    __shared__ int   s_wpos[4];
    __shared__ int   s_wneg[4];
    __shared__ int   s_last;

    const int blk = blockIdx.x;
    const int b   = blk >> 4;             // / SPLIT
    const int s   = blk & (SPLIT - 1);
    const int t   = threadIdx.x;
    const int js  = s * JS;

    // Vectorized staging: one float4 + one int4 per thread covers the row.
    const float4 sc = ((const float4*)(y_pred + (size_t)b * PRL_L))[t];
    const int4   lv = ((const int4*)  (y_true + (size_t)b * PRL_L))[t];

    float p[4];
    p[0] = (lv.x == 1) ? sc.x : 3.0e38f;
    p[1] = (lv.y == 1) ? sc.y : 3.0e38f;
    p[2] = (lv.z == 1) ? sc.z : 3.0e38f;
    p[3] = (lv.w == 1) ? sc.w : 3.0e38f;
    int cpos = (lv.x == 1) + (lv.y == 1) + (lv.z == 1) + (lv.w == 1);
    int cneg = 0;

    // Slice staging from registers: threads [js/4, js/4+16) own the slice.
    const int base = js >> 2;
    if ((unsigned)(t - base) < (unsigned)(JS / 4)) {
        float4 d;
        d.x = (lv.x == 0) ? (1.0f + sc.x) : -3.0e38f;
        d.y = (lv.y == 0) ? (1.0f + sc.y) : -3.0e38f;
        d.z = (lv.z == 0) ? (1.0f + sc.z) : -3.0e38f;
        d.w = (lv.w == 0) ? (1.0f + sc.w) : -3.0e38f;
        ((float4*)s_d)[t - base] = d;
        cneg = (lv.x == 0) + (lv.y == 0) + (lv.z == 0) + (lv.w == 0);
    }
    __syncthreads();

    // Hot loop: 16 wave-uniform float4 LDS broadcasts, 44 VALU ops each.
    float acc[4] = {0.f, 0.f, 0.f, 0.f};
    const float4* d4 = (const float4*)s_d;
#pragma unroll
    for (int c = 0; c < JS / 4; ++c) {
        const float4 d = d4[c];
#pragma unroll
        for (int k = 0; k < 4; ++k) {
            const float m0 = fmaxf(d.x - p[k], 0.0f) + fmaxf(d.y - p[k], 0.0f);
            const float m1 = fmaxf(d.z - p[k], 0.0f) + fmaxf(d.w - p[k], 0.0f);
            acc[k] += m0 + m1;
        }
    }
    float local = (acc[0] + acc[1]) + (acc[2] + acc[3]);

    // Block reduction: wave shuffle then LDS combine.
#pragma unroll
    for (int off = 32; off >= 1; off >>= 1) {
        local += __shfl_down(local, off, 64);
        cpos  += __shfl_down(cpos,  off, 64);
        cneg  += __shfl_down(cneg,  off, 64);
    }
    const int wave = t >> 6;
    if ((t & 63) == 0) { s_wsum[wave] = local; s_wpos[wave] = cpos; s_wneg[wave] = cneg; }
    __syncthreads();

    if (t == 0) {
        float rs = 0.f; int rp = 0, rn = 0;
#pragma unroll
        for (int w = 0; w < 4; ++w) { rs += s_wsum[w]; rp += s_wpos[w]; rn += s_wneg[w]; }
        // Distinct-slot plain stores: zero contention.
        bsum[blk]   = rs;
        bpairs[blk] = rp * rn;     // <= 1024*64, sums to < 2^31 over all blocks
        __threadfence();           // make partials L2-visible before signaling
        int last = 0;
        const int g = blk >> 6;    // / GRP
        const unsigned o1 = atomicAdd(&gc1[g * C1_STRIDE], 1u);
        if (o1 == GRP - 1) {       // last block of this group
            const unsigned o2 = atomicAdd(gc2, 1u);
            last = (o2 == NGRP - 1);
        }
        s_last = last;
    }
    __syncthreads();

    if (s_last) {
        __threadfence();           // order: counter observations -> partial reads
        // 256 threads x 8 partials each, vectorized.
        const float4* s4 = (const float4*)bsum;
        const int4*   p4 = (const int4*)bpairs;
        const float4 a = s4[2 * t], c = s4[2 * t + 1];
        const int4  ia = p4[2 * t], ic = p4[2 * t + 1];
        float fs = ((a.x + a.y) + (a.z + a.w)) + ((c.x + c.y) + (c.z + c.w));
        int   ps = (ia.x + ia.y + ia.z + ia.w) + (ic.x + ic.y + ic.z + ic.w);
#pragma unroll
        for (int off = 32; off >= 1; off >>= 1) {
            fs += __shfl_down(fs, off, 64);
            ps += __shfl_down(ps, off, 64);
        }
        if ((t & 63) == 0) { s_wsum[wave] = fs; s_wpos[wave] = ps; }
        __syncthreads();
        if (t == 0) {
            float total = 0.f; int pairs = 0;
#pragma unroll
            for (int w = 0; w < 4; ++w) { total += s_wsum[w]; pairs += s_wpos[w]; }
            out[0] = (pairs > 0) ? (total / fmaxf((float)pairs, 1.0f)) : total;
        }
    }
}

extern "C" void kernel_launch(void* const* d_in, const int* in_sizes, int n_in,
                              void* d_out, int out_size, void* d_ws, size_t ws_size,
                              hipStream_t stream) {
    const float* y_pred = (const float*)d_in[0];
    const int*   y_true = (const int*)d_in[1];
    float* out = (float*)d_out;

    // ws layout:
    //  [0, 4096):      u32 c1[NGRP] at stride C1_STRIDE u32 (128 B lines)
    //  [4096, 4100):   u32 c2
    //  [4352, 12544):  float bsum[NBLK]
    //  [12544, 20736): int bpairs[NBLK]
    unsigned int* gc1  = (unsigned int*)d_ws;
    unsigned int* gc2  = (unsigned int*)((char*)d_ws + 4096);
    float*        bsum = (float*)((char*)d_ws + 4352);
    int*         bpair = (int*)((char*)d_ws + 12544);

    hipMemsetAsync(d_ws, 0, 4352, stream);  // zero counters each call
    prl_fused<<<NBLK, 256, 0, stream>>>(y_pred, y_true, gc1, gc2, bsum, bpair, out);
}

// Round 5
// 15.301 us; speedup vs baseline: 6.0875x; 3.1484x over previous
//
#include <hip/hip_runtime.h>

// PairwiseRankingLoss: B=128 rows, L=1024.
// loss = sum_{b, pos i, neg j} relu(1 - s[b,i] + s[b,j]) / max(num_pairs, 1)
//
// Two kernels (kernel boundary = free device-scope ordering; no fences,
// no atomics, no memset):
//  K1: grid = B*SPLIT = 1024 blocks. Block (b,s) computes hinge over
//      (all i in row b) x (j in slice s), branchless via sentinels;
//      writes partial {sum, pos*neg_slice} to distinct ws slots.
//  K2: one 64-thread wave reduces the 1024 partials and writes the loss.

#define PRL_B 128
#define PRL_L 1024
#define SPLIT 8
#define JS    (PRL_L / SPLIT)   // 128 j's per block
#define NBLK  (PRL_B * SPLIT)   // 1024 blocks

__global__ __launch_bounds__(256) void prl_partial(
    const float* __restrict__ y_pred,
    const int*   __restrict__ y_true,
    float* __restrict__ bsum,    // [NBLK]
    int*   __restrict__ bpairs)  // [NBLK]
{
    __shared__ float s_d[JS];
    __shared__ float s_wsum[4];
    __shared__ int   s_wpos[4];
    __shared__ int   s_wneg[4];

    const int blk = blockIdx.x;
    const int b   = blk >> 3;             // / SPLIT
    const int s   = blk & (SPLIT - 1);
    const int t   = threadIdx.x;
    const int js  = s * JS;

    // Vectorized staging: one float4 + one int4 per thread covers the row.
    const float4 sc = ((const float4*)(y_pred + (size_t)b * PRL_L))[t];
    const int4   lv = ((const int4*)  (y_true + (size_t)b * PRL_L))[t];

    // Candidate-positive values (sentinel +3e38 -> pair contributes 0).
    float p[4];
    p[0] = (lv.x == 1) ? sc.x : 3.0e38f;
    p[1] = (lv.y == 1) ? sc.y : 3.0e38f;
    p[2] = (lv.z == 1) ? sc.z : 3.0e38f;
    p[3] = (lv.w == 1) ? sc.w : 3.0e38f;
    int cpos = (lv.x == 1) + (lv.y == 1) + (lv.z == 1) + (lv.w == 1);
    int cneg = 0;

    // Slice staging from registers: threads [js/4, js/4+32) own the slice.
    const int base = js >> 2;
    if ((unsigned)(t - base) < (unsigned)(JS / 4)) {
        float4 d;
        d.x = (lv.x == 0) ? (1.0f + sc.x) : -3.0e38f;
        d.y = (lv.y == 0) ? (1.0f + sc.y) : -3.0e38f;
        d.z = (lv.z == 0) ? (1.0f + sc.z) : -3.0e38f;
        d.w = (lv.w == 0) ? (1.0f + sc.w) : -3.0e38f;
        ((float4*)s_d)[t - base] = d;
        cneg = (lv.x == 0) + (lv.y == 0) + (lv.z == 0) + (lv.w == 0);
    }
    __syncthreads();

    // Hot loop: 32 wave-uniform float4 LDS broadcasts, 48 VALU ops each.
    float acc[4] = {0.f, 0.f, 0.f, 0.f};
    const float4* d4 = (const float4*)s_d;
#pragma unroll
    for (int c = 0; c < JS / 4; ++c) {
        const float4 d = d4[c];
#pragma unroll
        for (int k = 0; k < 4; ++k) {
            const float m0 = fmaxf(d.x - p[k], 0.0f) + fmaxf(d.y - p[k], 0.0f);
            const float m1 = fmaxf(d.z - p[k], 0.0f) + fmaxf(d.w - p[k], 0.0f);
            acc[k] += m0 + m1;
        }
    }
    float local = (acc[0] + acc[1]) + (acc[2] + acc[3]);

    // Block reduction: wave shuffle then LDS combine.
#pragma unroll
    for (int off = 32; off >= 1; off >>= 1) {
        local += __shfl_down(local, off, 64);
        cpos  += __shfl_down(cpos,  off, 64);
        cneg  += __shfl_down(cneg,  off, 64);
    }
    const int wave = t >> 6;
    if ((t & 63) == 0) { s_wsum[wave] = local; s_wpos[wave] = cpos; s_wneg[wave] = cneg; }
    __syncthreads();

    if (t == 0) {
        float rs = 0.f; int rp = 0, rn = 0;
#pragma unroll
        for (int w = 0; w < 4; ++w) { rs += s_wsum[w]; rp += s_wpos[w]; rn += s_wneg[w]; }
        // rp = full-row pos count; rn = this slice's negs.
        // sum_s rp*rn_s == rp*nneg_row, so the per-block products sum exactly.
        bsum[blk]   = rs;
        bpairs[blk] = rp * rn;    // <= 1024*128; total < 2^31
    }
}

// Single-wave finalize: 64 threads read all 1024 partials (8 KB, L2-hot),
// pure shuffle reduction, no syncthreads.
__global__ __launch_bounds__(64) void prl_finalize(
    const float* __restrict__ bsum,
    const int*   __restrict__ bpairs,
    float* __restrict__ out)
{
    const int t = threadIdx.x;
    const float4* s4 = (const float4*)bsum;
    const int4*   p4 = (const int4*)bpairs;

    float fs = 0.f; int ps = 0;
#pragma unroll
    for (int k = 0; k < 4; ++k) {           // 4 x 64 float4 = 1024 partials
        const float4 a = s4[t + 64 * k];
        const int4  ia = p4[t + 64 * k];
        fs += (a.x + a.y) + (a.z + a.w);
        ps += (ia.x + ia.y) + (ia.z + ia.w);
    }
#pragma unroll
    for (int off = 32; off >= 1; off >>= 1) {
        fs += __shfl_down(fs, off, 64);
        ps += __shfl_down(ps, off, 64);
    }
    if (t == 0)
        out[0] = (ps > 0) ? (fs / fmaxf((float)ps, 1.0f)) : fs;
}

extern "C" void kernel_launch(void* const* d_in, const int* in_sizes, int n_in,
                              void* d_out, int out_size, void* d_ws, size_t ws_size,
                              hipStream_t stream) {
    const float* y_pred = (const float*)d_in[0];
    const int*   y_true = (const int*)d_in[1];
    float* out = (float*)d_out;

    // ws layout: float bsum[NBLK]; int bpairs[NBLK]
    float* bsum   = (float*)d_ws;
    int*   bpairs = (int*)((char*)d_ws + NBLK * sizeof(float));

    prl_partial<<<NBLK, 256, 0, stream>>>(y_pred, y_true, bsum, bpairs);
    prl_finalize<<<1, 64, 0, stream>>>(bsum, bpairs, out);
}

// Round 6
// 11.751 us; speedup vs baseline: 7.9267x; 1.3021x over previous
//
#include <hip/hip_runtime.h>

// PairwiseRankingLoss: B=128 rows, L=1024.
// loss = sum_{b, pos i, neg j} relu(1 - s[b,i] + s[b,j]) / max(num_pairs, 1)
//
// K1: grid = B*SPLIT blocks. Each block ballot-compacts its row into dense
//     pos[] / neg[] LDS arrays (exact np, nn), then computes the hinge sum
//     over (all pos) x (its slice of negs) — ~4x fewer pair-slots than the
//     sentinel brute force. Partials to distinct ws slots; pair count is the
//     exact integer np*nn from slice 0.
// K2: one 64-thread wave reduces the partials and writes the loss.

#define PRL_B 128
#define PRL_L 1024
#define SPLIT 8
#define NBLK  (PRL_B * SPLIT)   // 1024 blocks

// Hot loop specialized on K = number of pos values per thread (block-uniform).
// All array indices compile-time after unrolling -> registers, no scratch.
template<int K>
__device__ __forceinline__ float hotloop(const float4* __restrict__ d4,
                                         int c0, int c1, float4 pv) {
    float acc[K];
#pragma unroll
    for (int k = 0; k < K; ++k) acc[k] = 0.f;
#pragma unroll 2
    for (int c = c0; c < c1; ++c) {
        const float4 d = d4[c];   // wave-uniform LDS broadcast
#pragma unroll
        for (int k = 0; k < K; ++k) {
            const float pk = (k == 0) ? pv.x : (k == 1) ? pv.y : (k == 2) ? pv.z : pv.w;
            acc[k] += (fmaxf(d.x - pk, 0.f) + fmaxf(d.y - pk, 0.f))
                    + (fmaxf(d.z - pk, 0.f) + fmaxf(d.w - pk, 0.f));
        }
    }
    float r = 0.f;
#pragma unroll
    for (int k = 0; k < K; ++k) r += acc[k];
    return r;
}

__global__ __launch_bounds__(256) void prl_partial(
    const float* __restrict__ y_pred,
    const int*   __restrict__ y_true,
    float* __restrict__ bsum,    // [NBLK]
    int*   __restrict__ bpairs)  // [NBLK]
{
    __shared__ float4 s_pos4[PRL_L / 4];   // compacted pos scores (+3e38 pad)
    __shared__ float4 s_neg4[PRL_L / 4];   // compacted 1+neg scores (-3e38 pad)
    __shared__ int    s_cntP[4], s_cntN[4];
    __shared__ float  s_wsum[4];
    float* s_pos = (float*)s_pos4;
    float* s_neg = (float*)s_neg4;

    const int blk  = blockIdx.x;
    const int b    = blk >> 3;            // / SPLIT
    const int s    = blk & (SPLIT - 1);
    const int t    = threadIdx.x;
    const int lane = t & 63;
    const int w    = t >> 6;

    // Vectorized staging: one float4 + one int4 per thread covers the row.
    const float4 sc = ((const float4*)(y_pred + (size_t)b * PRL_L))[t];
    const int4   lv = ((const int4*)  (y_true + (size_t)b * PRL_L))[t];
    const float sv[4] = {sc.x, sc.y, sc.z, sc.w};
    const int   lb[4] = {lv.x, lv.y, lv.z, lv.w};

    // Pass 1: per-wave pos/neg counts via ballot (elements 256w + 4*lane + r).
    unsigned long long mP[4], mN[4];
    int cP = 0, cN = 0;
#pragma unroll
    for (int r = 0; r < 4; ++r) {
        mP[r] = __ballot(lb[r] == 1);
        mN[r] = __ballot(lb[r] == 0);
        cP += (int)__popcll(mP[r]);
        cN += (int)__popcll(mN[r]);
    }
    if (lane == 0) { s_cntP[w] = cP; s_cntN[w] = cN; }

    // Sentinel-init the compact arrays (overwritten on [0,np)/[0,nn) below).
    s_pos4[t] = make_float4( 3.0e38f,  3.0e38f,  3.0e38f,  3.0e38f);
    s_neg4[t] = make_float4(-3.0e38f, -3.0e38f, -3.0e38f, -3.0e38f);
    __syncthreads();

    // Wave offsets + totals.
    int offP = 0, offN = 0, np = 0, nn = 0;
#pragma unroll
    for (int ww = 0; ww < 4; ++ww) {
        const int p_ = s_cntP[ww], n_ = s_cntN[ww];
        np += p_; nn += n_;
        if (ww < w) { offP += p_; offN += n_; }
    }

    // Pass 2: scatter compacted values (order within row is irrelevant).
    const unsigned long long lt = (1ULL << lane) - 1ULL;
    int bP = offP, bN = offN;
#pragma unroll
    for (int r = 0; r < 4; ++r) {
        if (lb[r] == 1) s_pos[bP + (int)__popcll(mP[r] & lt)] = sv[r];
        bP += (int)__popcll(mP[r]);
        if (lb[r] == 0) s_neg[bN + (int)__popcll(mN[r] & lt)] = 1.0f + sv[r];
        bN += (int)__popcll(mN[r]);
    }
    __syncthreads();

    // This thread's pos values (sentinel-padded reads are safe).
    const float4 pv = make_float4(s_pos[t], s_pos[t + 256],
                                  s_pos[t + 512], s_pos[t + 768]);
    const int KP  = (np + 255) >> 8;          // 0..4, block-uniform
    const int NN4 = (nn + 3) >> 2;            // float4 groups of negs
    const int G   = (NN4 + SPLIT - 1) >> 3;   // groups per slice
    const int c0  = s * G;
    const int c1  = min(c0 + G, NN4);

    float local;
    switch (KP) {
        case 0:  local = 0.f; break;
        case 1:  local = hotloop<1>(s_neg4, c0, c1, pv); break;
        case 2:  local = hotloop<2>(s_neg4, c0, c1, pv); break;
        case 3:  local = hotloop<3>(s_neg4, c0, c1, pv); break;
        default: local = hotloop<4>(s_neg4, c0, c1, pv); break;
    }

    // Block reduction: wave shuffle then LDS combine.
#pragma unroll
    for (int off = 32; off >= 1; off >>= 1)
        local += __shfl_down(local, off, 64);
    if (lane == 0) s_wsum[w] = local;
    __syncthreads();

    if (t == 0) {
        const float rs = (s_wsum[0] + s_wsum[1]) + (s_wsum[2] + s_wsum[3]);
        bsum[blk]   = rs;
        bpairs[blk] = (s == 0) ? np * nn : 0;   // exact pair count, once per row
    }
}

// Single-wave finalize: 64 threads read all 1024 partials (8 KB, L2-hot).
__global__ __launch_bounds__(64) void prl_finalize(
    const float* __restrict__ bsum,
    const int*   __restrict__ bpairs,
    float* __restrict__ out)
{
    const int t = threadIdx.x;
    const float4* s4 = (const float4*)bsum;
    const int4*   p4 = (const int4*)bpairs;

    float fs = 0.f; int ps = 0;
#pragma unroll
    for (int k = 0; k < 4; ++k) {           // 4 x 64 float4 = 1024 partials
        const float4 a = s4[t + 64 * k];
        const int4  ia = p4[t + 64 * k];
        fs += (a.x + a.y) + (a.z + a.w);
        ps += (ia.x + ia.y) + (ia.z + ia.w);
    }
#pragma unroll
    for (int off = 32; off >= 1; off >>= 1) {
        fs += __shfl_down(fs, off, 64);
        ps += __shfl_down(ps, off, 64);
    }
    if (t == 0)
        out[0] = (ps > 0) ? (fs / fmaxf((float)ps, 1.0f)) : fs;
}

extern "C" void kernel_launch(void* const* d_in, const int* in_sizes, int n_in,
                              void* d_out, int out_size, void* d_ws, size_t ws_size,
                              hipStream_t stream) {
    const float* y_pred = (const float*)d_in[0];
    const int*   y_true = (const int*)d_in[1];
    float* out = (float*)d_out;

    // ws layout: float bsum[NBLK]; int bpairs[NBLK]
    float* bsum   = (float*)d_ws;
    int*   bpairs = (int*)((char*)d_ws + NBLK * sizeof(float));

    prl_partial<<<NBLK, 256, 0, stream>>>(y_pred, y_true, bsum, bpairs);
    prl_finalize<<<1, 64, 0, stream>>>(bsum, bpairs, out);
}